// Round 8
// baseline (319.828 us; speedup 1.0000x reference)
//
#include <hip/hip_runtime.h>

// Problem constants (PARTViT pairwise head)
#define BB 64
#define NN 576
#define DD 768
#define KK 1024
#define ROWS (BB * NN)    // 36864 patch rows
#define PAIRS (BB * KK)   // 65536 pairs
// d_out layout: [PAIRS*2] f32 head output, then [PAIRS*2] f32 echoed indices
//
// R11: single-launch producer/consumer (asymmetric - NOT the R5 barrier).
// Ledger: R0/R8/R9/R10 = 169.2/166.4/168.4/168.1; five levers (structure,
// churn, MLP depth, issue order, occupancy) all <=3 us. Remaining split:
// (a) K1 intrinsically ~3 TB/s -> floor; (b) residual is inter-dispatch
// overhead in the replayed graph, which no K1-body change can touch. This
// round tests (b): one dispatch, 2560 blocks.
//   blocks [0,2304):  producers - R8's proven body (4 rows/wave straight-
//                     line, 12 dwordx4 up front), NEVER wait. Full churn.
//   blocks [2304,2560): consumers - dispatched last (grid order), each
//                     prefetches its 256 pair indices and writes the
//                     g_P-INDEPENDENT index echo (512 KB of out) BEFORE
//                     spinning on a monotonic done-counter, then gathers
//                     g_P and writes the head output.
// Counters are monotonic, never reset (graph-replay-safe): producers bump
// g_done once per block; consumers derive their round from their own g_rseq
// ticket (seq/256) -> target = (round+1)*2304. Bounded spin -> clean absmax
// failure, never a hang. Deadlock-free by capacity: 256 tiny spinner blocks
// cannot starve 2304 producers on 256 CUs.
// Pre-committed: null result (166 +/- 2) => declare ROOFLINE next round.

#define PROD_BLOCKS 2304   // ROWS / (4 waves * 4 rows)
#define CONS_BLOCKS 256
#define TPB 256
#define PAIRS_PER_CONS (PAIRS / CONS_BLOCKS)   // 256

// Per-patch projection table: P[r] = { z[r]·W[:768,0], z[r]·W[:768,1],
//                                      z[r]·W[768:,0], z[r]·W[768:,1] }
// Static device global (576 KB); fully rewritten each launch (replay-safe).
__device__ float4   g_P[ROWS];
__device__ unsigned g_done = 0;   // producer completions (monotonic)
__device__ unsigned g_rseq = 0;   // consumer tickets (monotonic)

__device__ __forceinline__ float4 rowdot(const float4 v[3],
                                         const float2 wa[3][4],
                                         const float2 wb[3][4]) {
    float s0 = 0.f, s1 = 0.f, s2 = 0.f, s3 = 0.f;
#pragma unroll
    for (int j = 0; j < 3; ++j) {
        const float e0 = v[j].x, e1 = v[j].y, e2 = v[j].z, e3 = v[j].w;
        s0 = fmaf(e0, wa[j][0].x, s0);
        s0 = fmaf(e1, wa[j][1].x, s0);
        s0 = fmaf(e2, wa[j][2].x, s0);
        s0 = fmaf(e3, wa[j][3].x, s0);
        s1 = fmaf(e0, wa[j][0].y, s1);
        s1 = fmaf(e1, wa[j][1].y, s1);
        s1 = fmaf(e2, wa[j][2].y, s1);
        s1 = fmaf(e3, wa[j][3].y, s1);
        s2 = fmaf(e0, wb[j][0].x, s2);
        s2 = fmaf(e1, wb[j][1].x, s2);
        s2 = fmaf(e2, wb[j][2].x, s2);
        s2 = fmaf(e3, wb[j][3].x, s2);
        s3 = fmaf(e0, wb[j][0].y, s3);
        s3 = fmaf(e1, wb[j][1].y, s3);
        s3 = fmaf(e2, wb[j][2].y, s3);
        s3 = fmaf(e3, wb[j][3].y, s3);
    }
    return make_float4(s0, s1, s2, s3);
}

// Interleaved dual butterfly: 8 independent add chains, 6 steps.
__device__ __forceinline__ void bfly2(float4& p, float4& q) {
#pragma unroll
    for (int off = 32; off > 0; off >>= 1) {
        p.x += __shfl_xor(p.x, off, 64);
        q.x += __shfl_xor(q.x, off, 64);
        p.y += __shfl_xor(p.y, off, 64);
        q.y += __shfl_xor(q.y, off, 64);
        p.z += __shfl_xor(p.z, off, 64);
        q.z += __shfl_xor(q.z, off, 64);
        p.w += __shfl_xor(p.w, off, 64);
        q.w += __shfl_xor(q.w, off, 64);
    }
}

__global__ __launch_bounds__(TPB, 4)
void partvit_pc(const float* __restrict__ z,
                const int* __restrict__ idx,
                const float* __restrict__ W,
                const float* __restrict__ bh,
                float* __restrict__ out) {
    if (blockIdx.x < PROD_BLOCKS) {
        // ================= producer: R8 body, verbatim =================
        const int lane = threadIdx.x & 63;
        const int wave = threadIdx.x >> 6;   // 0..3
        const int rbase = (blockIdx.x * 4 + wave) * 4;

        // All 12 row-loads (12 KB per wave) issued before anything else.
        const float4* __restrict__ z4 = (const float4*)z;  // 192 f4 per row
        float4 v[4][3];
#pragma unroll
        for (int rr = 0; rr < 4; ++rr)
#pragma unroll
            for (int j = 0; j < 3; ++j)
                v[rr][j] = z4[(size_t)(rbase + rr) * 192 + j * 64 + lane];

        // W is [1536,2] row-major: W[d,t] at 2*d+t -> float2 per d.
        // Lane l owns d = j*256 + 4l + c (j=0..2, c=0..3) of each half.
        const float2* __restrict__ W2 = (const float2*)W;
        float2 wa[3][4], wb[3][4];
#pragma unroll
        for (int j = 0; j < 3; ++j)
#pragma unroll
            for (int c = 0; c < 4; ++c) {
                const int d = j * 256 + (lane << 2) + c;
                wa[j][c] = W2[d];        // first-half weights (patch-0 slot)
                wb[j][c] = W2[d + DD];   // second-half weights (patch-1 slot)
            }

        float4 p0 = rowdot(v[0], wa, wb);
        float4 p1 = rowdot(v[1], wa, wb);
        bfly2(p0, p1);
        if (lane == 0)      g_P[rbase + 0] = p0;
        else if (lane == 1) g_P[rbase + 1] = p1;

        float4 p2 = rowdot(v[2], wa, wb);
        float4 p3 = rowdot(v[3], wa, wb);
        bfly2(p2, p3);
        if (lane == 0)      g_P[rbase + 2] = p2;
        else if (lane == 1) g_P[rbase + 3] = p3;

        // Publish: all stores retired (syncthreads drains vmcnt), then one
        // release-fenced arrival per block. Same pattern R5 proved correct.
        __syncthreads();
        if (threadIdx.x == 0) {
            __threadfence();
            atomicAdd(&g_done, 1u);
        }
    } else {
        // ================= consumer =================
        const int c = blockIdx.x - PROD_BLOCKS;
        const int t = c * PAIRS_PER_CONS + (int)threadIdx.x;  // pair = b*K+k

        // Work independent of g_P, done under/before the spin:
        const int2 id = ((const int2*)idx)[t];
        ((float2*)out)[PAIRS + t] = make_float2((float)id.x, (float)id.y);
        const float b0 = bh[0], b1 = bh[1];
        const int i0 = min(max(id.x, 0), NN - 1);   // clamp: dtype surprise
        const int i1 = min(max(id.y, 0), NN - 1);   // -> absmax, not fault
        const int b = t >> 10;  // K = 1024

        // Wait for this round's 2304 producer arrivals. Round derived from
        // this block's own monotonic ticket (256 consumers per replay).
        if (threadIdx.x == 0) {
            const unsigned seq = atomicAdd(&g_rseq, 1u);
            const unsigned target = (seq / CONS_BLOCKS + 1u) * PROD_BLOCKS;
            unsigned spins = 0;
            while (__hip_atomic_load(&g_done, __ATOMIC_RELAXED,
                                     __HIP_MEMORY_SCOPE_AGENT) < target) {
                if (++spins > (1u << 20)) break;  // clean fail, never hang
                __builtin_amdgcn_s_sleep(8);      // throttle polling traffic
            }
            __threadfence();  // acquire: fresh g_P reads
        }
        __syncthreads();

        const float4 p0 = g_P[b * NN + i0];
        const float4 p1 = g_P[b * NN + i1];
        ((float2*)out)[t] = make_float2(p0.x + p1.z + b0, p0.y + p1.w + b1);
    }
}

extern "C" void kernel_launch(void* const* d_in, const int* in_sizes, int n_in,
                              void* d_out, int out_size, void* d_ws, size_t ws_size,
                              hipStream_t stream) {
    const float* z   = (const float*)d_in[0];
    const int*   idx = (const int*)d_in[1];
    const float* W   = (const float*)d_in[2];
    const float* bh  = (const float*)d_in[3];
    float*       out = (float*)d_out;
    (void)d_ws; (void)ws_size; (void)in_sizes; (void)n_in; (void)out_size;

    // One dispatch: 2304 producer blocks first (grid order), 256 consumers last.
    partvit_pc<<<PROD_BLOCKS + CONS_BLOCKS, TPB, 0, stream>>>(z, idx, W, bh, out);
}

// Round 10
// 170.043 us; speedup vs baseline: 1.8809x; 1.8809x over previous
//
#include <hip/hip_runtime.h>
#include <stdint.h>

// Problem constants (PARTViT pairwise head)
#define BB 64
#define NN 576
#define DD 768
#define KK 1024
#define ROWS (BB * NN)    // 36864 patch rows
#define PAIRS (BB * KK)   // 65536 pairs
// d_out layout: [PAIRS*2] f32 head output, then [PAIRS*2] f32 echoed indices
//
// R13 = R12 resubmitted (R12 bench died on container infra, never ran).
// K1 rebuilt on the global_load_lds (direct-to-LDS DMA) path.
// Model after 12 rounds: every VGPR-return load variant pins at ~11 GB/s/CU
// (2.9 TB/s chip) regardless of TLP/MLP/order/churn -> consistent with a
// per-CU outstanding-cacheline cap (~40 lines) on the TCP return path;
// rate = outstanding/latency (R7's L2-hit gather: 23.8 GB/s/CU, exactly the
// latency ratio). Writes are uncapped (fills 6.9 TB/s). m97's GEMM sustains
// ~111 GB/s/CU of staging via global_load_lds -> the DMA path plausibly
// bypasses the cap. This round: stage z into LDS with the proven m97
// double-buffer template (stage t+1 -> compute t -> barrier; __syncthreads
// emits the vmcnt(0) drain), weights register-resident, butterfly reduce.
// R11 lesson (producer/consumer fused kernel, 199us): unified-kernel
// regalloc reintroduced the W-reload pathology (VGPR=56) + spin/fence
// overhead -> two-kernel structure is final.
// Pre-committed: null result (164-170 total) => ROOFLINE next round.

#define TPB 256
#define TILE_ROWS 4                 // rows per LDS tile (12 KB)
#define TILES 4                     // tiles per block -> 16 rows/block
#define K1_BLOCKS (ROWS / (TILES * TILE_ROWS))   // 2304

// Per-patch projection table: P[r] = { z[r]·W[:768,0], z[r]·W[:768,1],
//                                      z[r]·W[768:,0], z[r]·W[768:,1] }
// Static device global (576 KB); fully rewritten each launch (replay-safe).
__device__ float4 g_P[ROWS];

// Direct global->LDS DMA, 16 B per lane. LDS dest = wave-uniform base +
// lane*16 (HW rule); global src is per-lane. Size must be a literal 16.
// Casts via uintptr_t: conservative spelling of generic->AS(1)/AS(3).
__device__ __forceinline__ void gload_lds16(const float4* g, float4* l) {
    __builtin_amdgcn_global_load_lds(
        (const __attribute__((address_space(1))) void*)(uintptr_t)g,
        (__attribute__((address_space(3))) void*)(uintptr_t)(
            (char*)l - (char*)nullptr ? (void*)l : (void*)l),
        16, 0, 0);
}

__device__ __forceinline__ float4 rowdot(const float4 v[3],
                                         const float2 wa[3][4],
                                         const float2 wb[3][4]) {
    float s0 = 0.f, s1 = 0.f, s2 = 0.f, s3 = 0.f;
#pragma unroll
    for (int j = 0; j < 3; ++j) {
        const float e0 = v[j].x, e1 = v[j].y, e2 = v[j].z, e3 = v[j].w;
        s0 = fmaf(e0, wa[j][0].x, s0);
        s0 = fmaf(e1, wa[j][1].x, s0);
        s0 = fmaf(e2, wa[j][2].x, s0);
        s0 = fmaf(e3, wa[j][3].x, s0);
        s1 = fmaf(e0, wa[j][0].y, s1);
        s1 = fmaf(e1, wa[j][1].y, s1);
        s1 = fmaf(e2, wa[j][2].y, s1);
        s1 = fmaf(e3, wa[j][3].y, s1);
        s2 = fmaf(e0, wb[j][0].x, s2);
        s2 = fmaf(e1, wb[j][1].x, s2);
        s2 = fmaf(e2, wb[j][2].x, s2);
        s2 = fmaf(e3, wb[j][3].x, s2);
        s3 = fmaf(e0, wb[j][0].y, s3);
        s3 = fmaf(e1, wb[j][1].y, s3);
        s3 = fmaf(e2, wb[j][2].y, s3);
        s3 = fmaf(e3, wb[j][3].y, s3);
    }
    return make_float4(s0, s1, s2, s3);
}

// Kernel 1: LDS-staged streaming projection.
// Block: 16 contiguous rows as 4 tiles of 4 rows; 2-deep LDS double buffer
// (24 KB -> LDS allows 6 blocks/CU; launch_bounds caps regs for 4). Per
// tile: 12 KB staged by 12 DMA instrs (3 per wave); wave w computes row w
// of the tile (3 ds_read_b128 + 48 FMA + 64-lane butterfly); one barrier
// per tile. DMA for tile t+1 issued BEFORE compute of tile t so its flight
// overlaps compute; the barrier's implicit vmcnt(0) drain lands after
// compute (m97 schedule).
__global__ __launch_bounds__(TPB, 4)
void partvit_proj(const float* __restrict__ z, const float* __restrict__ W) {
    __shared__ float4 buf[2][TILE_ROWS * 192];   // 2 x 12 KB
    const int lane = threadIdx.x & 63;
    const int wave = threadIdx.x >> 6;           // 0..3
    const int rbase = blockIdx.x * (TILES * TILE_ROWS);

    const float4* __restrict__ z4 = (const float4*)z;  // 192 float4 per row

    // Weights -> registers (48 VGPR), loaded once per block, amortized over
    // 16 rows. W is [1536,2] row-major: W[d,t] at 2*d+t -> float2 per d.
    // Lane l owns d = j*256 + 4l + c (j=0..2, c=0..3) of each half.
    const float2* __restrict__ W2 = (const float2*)W;
    float2 wa[3][4], wb[3][4];
#pragma unroll
    for (int j = 0; j < 3; ++j)
#pragma unroll
        for (int c = 0; c < 4; ++c) {
            const int d = j * 256 + (lane << 2) + c;
            wa[j][c] = W2[d];        // first-half weights (patch-0 slot)
            wb[j][c] = W2[d + DD];   // second-half weights (patch-1 slot)
        }

    // Prologue: stage tile 0. Each wave stages 3 contiguous 1 KB chunks.
#pragma unroll
    for (int k = 0; k < 3; ++k) {
        const int chunk = wave * 3 + k;          // 0..11 over the tile
        gload_lds16(&z4[(size_t)rbase * 192 + chunk * 64 + lane],
                    &buf[0][chunk * 64]);
    }
    __syncthreads();   // compiler emits vmcnt(0) drain before s_barrier

#pragma unroll
    for (int t = 0; t < TILES; ++t) {
        // Stage tile t+1 first: DMA flight overlaps this tile's compute.
        if (t + 1 < TILES) {
            const size_t base = ((size_t)rbase + (size_t)(t + 1) * TILE_ROWS) * 192;
#pragma unroll
            for (int k = 0; k < 3; ++k) {
                const int chunk = wave * 3 + k;
                gload_lds16(&z4[base + chunk * 64 + lane],
                            &buf[(t + 1) & 1][chunk * 64]);
            }
        }

        // Compute: wave w owns row (rbase + t*4 + w) of buf[t&1].
        float4 v[3];
#pragma unroll
        for (int j = 0; j < 3; ++j)
            v[j] = buf[t & 1][wave * 192 + j * 64 + lane];

        float4 p = rowdot(v, wa, wb);
#pragma unroll
        for (int off = 32; off > 0; off >>= 1) {
            p.x += __shfl_xor(p.x, off, 64);
            p.y += __shfl_xor(p.y, off, 64);
            p.z += __shfl_xor(p.z, off, 64);
            p.w += __shfl_xor(p.w, off, 64);
        }
        if (lane == 0) g_P[rbase + t * TILE_ROWS + wave] = p;

        __syncthreads();  // next-tile DMA drained + LDS reuse safe
    }
}

// Kernel 2 (verbatim R0): out = P[i0].xy + P[i1].zw + bias ; echo indices.
// Indices clamped to [0, NN-1] so a dtype-contract surprise yields a clean
// absmax failure instead of a memory fault.
__global__ __launch_bounds__(TPB) void partvit_pairs(const int* __restrict__ idx,
                                                     const float* __restrict__ bh,
                                                     float* __restrict__ out) {
    const int t = blockIdx.x * blockDim.x + threadIdx.x;  // pair id = b*K + k
    if (t >= PAIRS) return;
    const int2 id = ((const int2*)idx)[t];
    const int i0 = min(max(id.x, 0), NN - 1);
    const int i1 = min(max(id.y, 0), NN - 1);
    const int b = t >> 10;  // K = 1024
    const float4 p0 = g_P[b * NN + i0];
    const float4 p1 = g_P[b * NN + i1];
    const float b0 = bh[0], b1 = bh[1];
    ((float2*)out)[t] = make_float2(p0.x + p1.z + b0, p0.y + p1.w + b1);
    ((float2*)out)[PAIRS + t] = make_float2((float)id.x, (float)id.y);
}

extern "C" void kernel_launch(void* const* d_in, const int* in_sizes, int n_in,
                              void* d_out, int out_size, void* d_ws, size_t ws_size,
                              hipStream_t stream) {
    const float* z   = (const float*)d_in[0];
    const int*   idx = (const int*)d_in[1];
    const float* W   = (const float*)d_in[2];
    const float* bh  = (const float*)d_in[3];
    float*       out = (float*)d_out;
    (void)d_ws; (void)ws_size; (void)in_sizes; (void)n_in; (void)out_size;

    // K1: 2304 blocks * 4 waves; 16 rows/block via 4 double-buffered tiles.
    partvit_proj<<<K1_BLOCKS, TPB, 0, stream>>>(z, W);
    // K2: one thread per pair.
    partvit_pairs<<<PAIRS / TPB, TPB, 0, stream>>>(idx, bh, out);
}